// Round 1
// baseline (573.430 us; speedup 1.0000x reference)
//
#include <hip/hip_runtime.h>
#include <hip/hip_bf16.h>

// FrameOTAMDistanceNetwork: per (s,b): 8x8 cosine matrix between 8 support
// frames and 8 target frames (each 2048 fp32), then OTAM soft-DP both ways.
// Memory-bound: 436 MB compulsory reads -> ~70us floor at 6.3 TB/s.

constexpr int kNF   = 8;
constexpr int kFLEN = 2048;   // DF / NFRAMES
constexpr int kSeq  = 25;
constexpr int kBS   = 256;
constexpr int kDF   = 16384;
constexpr float kLam    = 0.1f;
constexpr float kInvLam = 10.0f;

__global__ __launch_bounds__(256, 2) void otam_kernel(
    const float* __restrict__ sv,   // [Seq, BS, DF]
    const float* __restrict__ tv,   // [BS, DF]
    float* __restrict__ out)        // [Seq, BS]
{
    __shared__ float V[kDF];            // 64 KB: target frames for this b
    __shared__ float sdot[kNF][kNF];    // raw dot(u_i, v_j)
    __shared__ float snu[kNF];          // |u_i|^2
    __shared__ float snv[kNF];          // |v_j|^2
    __shared__ float sD[kNF][kNF];      // normalized cosine matrix

    const int bid = blockIdx.x;
    const int s = bid % kSeq;           // consecutive blocks share tv[b] -> L2 locality
    const int b = bid / kSeq;
    const int t = threadIdx.x;

    // ---- stage tv[b] into LDS (4096 float4, coalesced) ----
    {
        const float4* tv4 = (const float4*)(tv + (size_t)b * kDF);
        float4* V4 = (float4*)V;
        #pragma unroll
        for (int it = 0; it < 16; ++it)
            V4[it * 256 + t] = tv4[it * 256 + t];
    }
    __syncthreads();

    const int g = t >> 5;   // group 0..7: owns support frame g (and v-norm of frame g)
    const int l = t & 31;   // lane within group

    // ---- v norms: group g computes |v_g|^2 from LDS ----
    float v2 = 0.f;
    {
        const float4* Vg = (const float4*)(V + g * kFLEN);
        #pragma unroll 4
        for (int c = 0; c < 16; ++c) {
            float4 v = Vg[c * 32 + l];
            v2 = fmaf(v.x, v.x, v2); v2 = fmaf(v.y, v.y, v2);
            v2 = fmaf(v.z, v.z, v2); v2 = fmaf(v.w, v.w, v2);
        }
    }

    // ---- dots: group g's support frame vs all 8 target frames ----
    float dot[kNF] = {};
    float u2 = 0.f;
    const float4* U4 = (const float4*)(sv + ((size_t)s * kBS + b) * kDF + (size_t)g * kFLEN);
    #pragma unroll 4
    for (int c = 0; c < 16; ++c) {
        float4 u = U4[c * 32 + l];   // half-wave reads contiguous 512B
        u2 = fmaf(u.x, u.x, fmaf(u.y, u.y, fmaf(u.z, u.z, fmaf(u.w, u.w, u2))));
        #pragma unroll
        for (int j = 0; j < kNF; ++j) {
            // both halves of the wave read identical V addresses -> broadcast, free
            float4 v = ((const float4*)(V + j * kFLEN))[c * 32 + l];
            dot[j] = fmaf(u.x, v.x, fmaf(u.y, v.y, fmaf(u.z, v.z, fmaf(u.w, v.w, dot[j]))));
        }
    }

    // ---- reduce 10 values across the 32-lane group (xor masks <=16 stay in-half) ----
    #pragma unroll
    for (int m = 16; m >= 1; m >>= 1) {
        u2 += __shfl_xor(u2, m, 64);
        v2 += __shfl_xor(v2, m, 64);
        #pragma unroll
        for (int j = 0; j < kNF; ++j) dot[j] += __shfl_xor(dot[j], m, 64);
    }
    if (l == 0) {
        snu[g] = u2;
        snv[g] = v2;
        #pragma unroll
        for (int j = 0; j < kNF; ++j) sdot[g][j] = dot[j];
    }
    __syncthreads();

    // ---- normalize into sD (64 lanes, one per (i,j)) ----
    if (t < 64) {
        const int i = t >> 3, j = t & 7;
        sD[i][j] = sdot[i][j] * rsqrtf(snu[i]) * rsqrtf(snv[j]);
    }
    __syncthreads();

    // ---- two DPs on lanes 0..15 of wave 0: lanes 0-7 dp(D), lanes 8-15 dp(D^T) ----
    if (t < 16) {
        const int r = t & 7;
        const bool xp = (t >= 8);

        auto Dm = [&](int rr, int ii) -> float {
            return xp ? sD[ii][rr] : sD[rr][ii];
        };

        float prev = Dm(r, 0);
        #pragma unroll
        for (int i = 1; i < kNF; ++i) {
            float up = __shfl_up(prev, 1, 64);  // prev[r-1]; unused when r==0
            float d  = Dm(r, i);
            float mx = fmaxf(up, prev);
            float mn = fminf(up, prev);
            float lse = mx + kLam * log1pf(expf((mn - mx) * kInvLam));
            prev = (r == 0) ? (prev + d) : (lse + d);
        }
        // final lam*logsumexp over the 8 rows (xor masks 4,2,1 stay in 8-lane group)
        float mx = prev;
        #pragma unroll
        for (int m = 4; m >= 1; m >>= 1) mx = fmaxf(mx, __shfl_xor(mx, m, 64));
        float e = expf((prev - mx) * kInvLam);
        #pragma unroll
        for (int m = 4; m >= 1; m >>= 1) e += __shfl_xor(e, m, 64);
        float res = mx + kLam * logf(e);

        float resT = __shfl(res, (t & 7) + 8, 64);  // pair each dp1 lane with dp2 lane
        if (t == 0) out[(size_t)s * kBS + b] = 0.5f * (res + resT);
    }
}

extern "C" void kernel_launch(void* const* d_in, const int* in_sizes, int n_in,
                              void* d_out, int out_size, void* d_ws, size_t ws_size,
                              hipStream_t stream) {
    const float* sv = (const float*)d_in[0];
    const float* tv = (const float*)d_in[1];
    float* out = (float*)d_out;
    otam_kernel<<<dim3(kSeq * kBS), dim3(256), 0, stream>>>(sv, tv, out);
}